// Round 1
// baseline (238.809 us; speedup 1.0000x reference)
//
#include <hip/hip_runtime.h>
#include <math.h>

// Problem constants
#define A_N   8400
#define BS    32
#define NGT   64
#define NC    80
#define TK    13
#define EPSF  1e-9f
#define CAP   1024          // dense per-(b,gt) candidate list capacity
#define JG    16            // gts per k_cand block (64 split in 4 groups)
#define NJG   4
#define NTILE 33            // ceil(8400/256)
#define PCAP  64            // LDS pool capacity per (block, gt)
#define NCAND (BS * NTILE * NJG)   // 4224 k_cand blocks
#define FGCAP (BS * NGT * TK)      // 26624: hard bound on fg anchors (<=13 picks/gt)

typedef float nt4 __attribute__((ext_vector_type(4)));   // native vec for nontemporal store

// Output layout (floats), concatenated in reference return order
#define OFF_LB 0
#define OFF_BB (BS * A_N)
#define OFF_SC (OFF_BB + BS * A_N * 4)
#define OFF_FG (OFF_SC + BS * A_N * NC)

// Workspace layout (byte offsets, all 256-aligned)
// R8: dropped WS_FLAG/WS_INFO/WS_ALIGN (flag now via in-kernel ballot; info/align
// replaced by compact fg record list). posA/posO/cnt2/fgCnt contiguous -> one k_zero.
#define WS_CNT   0
#define WS_MINJ  (WS_CNT  + BS * A_N * 4)
#define WS_POSA  (WS_MINJ + BS * A_N * 4)
#define WS_POSO  (WS_POSA + BS * NGT * 4)
#define WS_CNT2  (WS_POSO + BS * NGT * 4)
#define WS_FGC   (WS_CNT2 + BS * NGT * 4)
#define WS_FGL   (WS_FGC  + 256)
#define WS_CAND  (WS_FGL  + FGCAP * 16)
// total ~= 19.4 MB (was 21.1 MB)

// NOTE (R7 lesson): software grid barriers (device-scope atomic spin) cost
// ~250 us EACH on MI355X — 768 blocks spinning on one cacheline starve the
// workers. Separate kernel launches (~2 us gap) are 100x cheaper. Never fuse
// dependent grid-wide phases with a spin barrier here.
//
// NOTE (R8 diagnostic): rocprof top-5 is 100% harness re-poison fills (370 MB
// @6.6 TB/s); our dispatches are each <55 us. Bottom-up model of the 5 kernels
// sums to ~45 us vs 210 us measured -> suspect ~160 us fixed harness overhead
// inside the timed region. If this round's trims (-k_init work, -3 MB traffic,
// k_norm 1050->104 blocks) move dur by <2 us, that hypothesis is confirmed.

__device__ __forceinline__ float iou_f(float g0, float g1, float g2, float g3,
                                       float p0, float p1, float p2, float p3) {
    float ltx = fmaxf(g0, p0), lty = fmaxf(g1, p1);
    float rbx = fminf(g2, p2), rby = fminf(g3, p3);
    float ov  = fmaxf(rbx - ltx, 0.f) * fmaxf(rby - lty, 0.f);
    float a1  = fmaxf(g2 - g0, 0.f) * fmaxf(g3 - g1, 0.f);
    float a2  = fmaxf(p2 - p0, 0.f) * fmaxf(p3 - p1, 0.f);
    return ov / (a1 + a2 - ov + EPSF);
}

__device__ __forceinline__ int get_gl(const int* g, int flag64, int i) {
    return flag64 ? g[2 * i] : g[i];
}

// int64-vs-int32 gt_labels layout probe: wave 0 checks the high words of the
// first 64 entries (same heuristic as the old k_init, now launch-free).
// Returns valid value in every lane of wave 0 only.
__device__ __forceinline__ int probe_flag64_wave0(const int* gl_raw, int tid) {
    int f64 = 0;
    if (tid < 64) {
        unsigned long long m = __ballot(gl_raw[2 * tid + 1] != 0);
        f64 = (m == 0ull);
    }
    return f64;
}

__device__ __forceinline__ unsigned long long shfl_xor_u64(unsigned long long x, int m) {
    int lo = __shfl_xor((int)(unsigned int)(x & 0xFFFFFFFFull), m, 64);
    int hi = __shfl_xor((int)(unsigned int)(x >> 32), m, 64);
    return ((unsigned long long)(unsigned int)hi << 32) | (unsigned int)lo;
}

// ---------------- Kernel 0: zero the small counter block ---------------------
// posA(2048) + posO(2048) + cnt2(2048) + fgCnt slot(64) = 6208 ints, contiguous.
__global__ __launch_bounds__(256) void k_zero(int* __restrict__ base) {
    int i = blockIdx.x * 256 + threadIdx.x;
    if (i < 3 * BS * NGT + 64) base[i] = 0;
}

// ---------------- Kernel 1: dense in-box sweep -> candidate lists ------------
// Absorbed zero-fills run POST-barrier (drain at kernel retire only, overlap
// other blocks' latency-bound hit loops).
__global__ __launch_bounds__(256) void k_cand(
    const float* __restrict__ pd_scores, const float* __restrict__ pd_bboxes,
    const float* __restrict__ anc, const int* __restrict__ gl_raw,
    const float* __restrict__ gt_bboxes, const float* __restrict__ mask_gt,
    int* __restrict__ cnt2, unsigned long long* __restrict__ cand,
    int* __restrict__ cnt, int* __restrict__ minj, float* __restrict__ out) {
    __shared__ float4 sgt[JG];
    __shared__ int    slbl[JG];
    __shared__ int    smask[JG];
    __shared__ int    cnt_lds[JG];
    __shared__ int    base_lds[JG];
    __shared__ unsigned long long pool[JG][PCAP];

    int bid  = blockIdx.x;
    int b    = bid / (NTILE * NJG);
    int rem  = bid % (NTILE * NJG);
    int tile = rem / NJG;
    int jg   = rem % NJG;
    int tid  = threadIdx.x;
    int a    = tile * 256 + tid;
    int jbase = b * NGT + jg * JG;

    int f64 = probe_flag64_wave0(gl_raw, tid);    // valid in wave 0 (tids 0..63)
    if (tid < JG) {                               // tid<16 is inside wave 0
        sgt[tid]   = ((const float4*)gt_bboxes)[jbase + tid];
        slbl[tid]  = get_gl(gl_raw, f64, jbase + tid);
        smask[tid] = (mask_gt[jbase + tid] != 0.f);
        cnt_lds[tid] = 0;
    }
    __syncthreads();

    bool act = (a < A_N);
    float2 an = make_float2(0.f, 0.f);
    float4 p  = make_float4(0.f, 0.f, 0.f, 0.f);
    const float* sc = pd_scores;
    if (act) {
        an = ((const float2*)anc)[a];
        p  = ((const float4*)pd_bboxes)[(size_t)b * A_N + a];
        sc = pd_scores + (size_t)b * A_N * NC + (size_t)a * NC;
    }

    // Phase A: hit detection + LDS append
    for (int j = 0; j < JG; j++) {
        if (!smask[j]) continue;                       // block-uniform
        if (!act) continue;
        float4 g = sgt[j];
        float d = fminf(fminf(an.x - g.x, an.y - g.y),
                        fminf(g.z - an.x, g.w - an.y));
        if (d > EPSF) {
            float iou = iou_f(g.x, g.y, g.z, g.w, p.x, p.y, p.z, p.w);
            float m = 0.f;
            if (iou > 0.f) {
                float s = sc[slbl[j]];
                m = s * powf(iou, 6.0f);               // identical op order (absmax 0.0)
            }
            unsigned long long key =
                ((unsigned long long)__float_as_uint(m) << 32) |
                (unsigned int)(~(unsigned int)a);      // (metric desc, anchor asc) under max
            int slot = atomicAdd(&cnt_lds[j], 1);      // LDS atomic
            if (slot < PCAP) {
                pool[j][slot] = key;
            } else {                                   // rare overflow: direct global
                int gs = atomicAdd(&cnt2[jbase + j], 1);
                if (gs < CAP) cand[(size_t)(jbase + j) * CAP + gs] = key;
            }
        }
    }
    __syncthreads();

    // Phase B: one global reservation per gt, issued in parallel
    if (tid < JG) {
        int c = min(cnt_lds[tid], PCAP);
        int bas = 0;
        if (c > 0) bas = atomicAdd(&cnt2[jbase + tid], c);
        base_lds[tid] = bas;
    }
    __syncthreads();

    // Phase C: flush LDS pools to global
    for (int j = 0; j < JG; j++) {
        int c = min(cnt_lds[j], PCAP);
        int bas = base_lds[j];
        for (int t = tid; t < c; t += 256) {
            int dst = bas + t;
            if (dst < CAP) cand[(size_t)(jbase + j) * CAP + dst] = pool[j][t];
        }
    }

    // Phase D (post-barrier): absorbed zero-fills; drain at kernel retire only
    {
        int gth = bid * 256 + tid;
        const int GS = NCAND * 256;
        nt4* scz = (nt4*)(out + OFF_SC);
        for (int t = gth; t < BS * A_N * (NC / 4); t += GS)
            __builtin_nontemporal_store((nt4)(0.f), &scz[t]);
        for (int t = gth; t < BS * A_N; t += GS) {
            cnt[t] = 0; minj[t] = 1 << 30;
        }
    }
}

// ---------------- Kernel 2: per-(b,gt) wave top-13 + scatter -----------------
template <int NT>
__device__ __forceinline__ void pick_body(
    int lane, int b, int j, int n, const unsigned long long* __restrict__ L,
    int* __restrict__ cnt, int* __restrict__ minj) {
    unsigned long long k0[NT];
    #pragma unroll
    for (int t = 0; t < NT; t++) {
        int i = t * 64 + lane;
        k0[t] = (i < n) ? L[i] : 0ULL;                 // 0 = empty (real keys nonzero)
    }

    unsigned int wanchor[TK];
    int P = 0;
    #pragma unroll
    for (int r = 0; r < TK; r++) {
        unsigned long long best = 0;
        #pragma unroll
        for (int t = 0; t < NT; t++) best = (k0[t] > best) ? k0[t] : best;
        for (int s = 1; s < 64; s <<= 1) {
            unsigned long long o = shfl_xor_u64(best, s);
            if (o > best) best = o;
        }
        if (!(best >> 32)) break;                      // out of positive metrics
        unsigned int aw = ~(unsigned int)(best & 0xFFFFFFFFull);
        wanchor[r] = aw;
        if (lane == 0) {
            atomicAdd(&cnt[b * A_N + (int)aw], 1);
            atomicMin(&minj[b * A_N + (int)aw], j);
        }
        #pragma unroll
        for (int t = 0; t < NT; t++) if (k0[t] == best) k0[t] = 0;
        P++;
    }

    // Fillers: top_k back-fills (13-P) lowest-index zero-metric anchors of the
    // full array; only in-box ones (all present as zero-metric candidates)
    // survive mask_in_gts. a is a filler iff a - |{positive winners < a}| < 13-P.
    if (P < TK) {
        int K = TK - P;
        #pragma unroll
        for (int t = 0; t < NT; t++) {
            unsigned long long key = k0[t];
            if (key != 0 && !(key >> 32)) {
                unsigned int a0 = ~(unsigned int)(key & 0xFFFFFFFFull);
                int off = 0;
                #pragma unroll
                for (int r = 0; r < TK; r++)
                    if (r < P && wanchor[r] < a0) off++;
                if ((int)a0 < K + off) {
                    atomicAdd(&cnt[b * A_N + (int)a0], 1);
                    atomicMin(&minj[b * A_N + (int)a0], j);
                }
            }
        }
    }
}

__global__ __launch_bounds__(256) void k_pick(
    const int* __restrict__ cnt2, const unsigned long long* __restrict__ cand,
    int* __restrict__ cnt, int* __restrict__ minj) {
    int lane = threadIdx.x & 63;
    int wave = threadIdx.x >> 6;
    int bj = blockIdx.x * 4 + wave;
    int b = bj >> 6, j = bj & 63;

    int n = min(cnt2[bj], CAP);
    if (n == 0) return;                                // wave-uniform
    const unsigned long long* L = cand + (size_t)bj * CAP;

    // wave-uniform tier dispatch: compile-time bounds keep k0[] in registers
    if (n <= 128)      pick_body<2>(lane, b, j, n, L, cnt, minj);
    else if (n <= 320) pick_body<5>(lane, b, j, n, L, cnt, minj);
    else               pick_body<16>(lane, b, j, n, L, cnt, minj);
}

// ---------------- Kernel 3: per-anchor assignment + labels/bboxes/fg ---------
// R8: emits a compact fg record (packed i|lbl, bj, align) instead of the dense
// info/alignArr arrays (-2 MB writes; k_norm no longer sweeps all anchors).
__global__ __launch_bounds__(256) void k_assign(
    const float* __restrict__ pd_scores, const float* __restrict__ pd_bboxes,
    const float* __restrict__ gt_bboxes, const int* __restrict__ gl_raw,
    const int* __restrict__ cnt, const int* __restrict__ minj,
    unsigned int* posA, unsigned int* posO,
    int4* __restrict__ fgList, int* __restrict__ fgCnt, float* __restrict__ out) {
    __shared__ int sfl;
    if (threadIdx.x < 64) {
        int f = probe_flag64_wave0(gl_raw, threadIdx.x);
        if (threadIdx.x == 0) sfl = f;
    }
    __syncthreads();

    int i = blockIdx.x * 256 + threadIdx.x;
    if (i >= BS * A_N) return;                    // grid is exact (1050*256), kept for safety
    int b = i / A_N;
    int c = cnt[i];
    int f64 = sfl;

    float4 p = ((const float4*)pd_bboxes)[i];
    int jstar = 0;
    if (c == 1) {
        jstar = minj[i];
    } else if (c > 1) {
        float bv = -1.f; int bj_ = 0;
        const float4* gb = (const float4*)(gt_bboxes + (size_t)b * NGT * 4);
        for (int j = 0; j < NGT; j++) {
            float4 g = gb[j];
            float ov = iou_f(g.x, g.y, g.z, g.w, p.x, p.y, p.z, p.w);
            if (ov > bv) { bv = ov; bj_ = j; }
        }
        jstar = bj_;
    }

    int lbl = get_gl(gl_raw, f64, b * NGT + jstar);
    if (lbl < 0) lbl = 0;

    out[OFF_LB + i] = (float)lbl;
    float4 g = ((const float4*)gt_bboxes)[b * NGT + jstar];
    ((float4*)(out + OFF_BB))[i] = g;

    int fg = (c > 0) ? 1 : 0;
    out[OFF_FG + i] = (float)fg;

    if (fg) {
        float ov = iou_f(g.x, g.y, g.z, g.w, p.x, p.y, p.z, p.w);
        float s  = pd_scores[(size_t)i * NC + lbl];
        float al = s * powf(ov, 6.0f);
        atomicMax((int*)&posA[b * NGT + jstar], __float_as_int(al));
        atomicMax((int*)&posO[b * NGT + jstar], __float_as_int(ov));
        int slot = atomicAdd(fgCnt, 1);           // bounded by FGCAP (<=13 picks/gt)
        fgList[slot] = make_int4(i | (lbl << 20), b * NGT + jstar,
                                 __float_as_int(al), 0);
    }
}

// ---------------- Kernel 4: sparse norm scatter over compact fg list ---------
__global__ __launch_bounds__(256) void k_norm(
    const int4* __restrict__ fgList, const int* __restrict__ fgCnt,
    const unsigned int* __restrict__ posA, const unsigned int* __restrict__ posO,
    float* __restrict__ out) {
    int t = blockIdx.x * 256 + threadIdx.x;
    if (t >= *fgCnt) return;
    int4 r  = fgList[t];
    int i   = r.x & 0xFFFFF;
    int lbl = r.x >> 20;
    int bj  = r.y;
    float al = __int_as_float(r.z);
    float pa = __int_as_float((int)posA[bj]);
    float po = __int_as_float((int)posO[bj]);
    out[OFF_SC + (size_t)i * NC + lbl] = al * po / (pa + EPSF);
}

extern "C" void kernel_launch(void* const* d_in, const int* in_sizes, int n_in,
                              void* d_out, int out_size, void* d_ws, size_t ws_size,
                              hipStream_t stream) {
    const float* pd_scores = (const float*)d_in[0];
    const float* pd_bboxes = (const float*)d_in[1];
    const float* anc       = (const float*)d_in[2];
    const int*   gl_raw    = (const int*)d_in[3];
    const float* gt_bboxes = (const float*)d_in[4];
    const float* mask_gt   = (const float*)d_in[5];
    float* out = (float*)d_out;

    char* ws = (char*)d_ws;
    int*                cnt      = (int*)(ws + WS_CNT);
    int*                minj     = (int*)(ws + WS_MINJ);
    unsigned int*       posA     = (unsigned int*)(ws + WS_POSA);
    unsigned int*       posO     = (unsigned int*)(ws + WS_POSO);
    int*                cnt2     = (int*)(ws + WS_CNT2);
    int*                fgCnt    = (int*)(ws + WS_FGC);
    int4*               fgList   = (int4*)(ws + WS_FGL);
    unsigned long long* cand     = (unsigned long long*)(ws + WS_CAND);

    k_zero<<<25, 256, 0, stream>>>((int*)(ws + WS_POSA));
    k_cand<<<NCAND, 256, 0, stream>>>(pd_scores, pd_bboxes, anc, gl_raw,
                                      gt_bboxes, mask_gt, cnt2, cand,
                                      cnt, minj, out);
    k_pick<<<BS * NGT / 4, 256, 0, stream>>>(cnt2, cand, cnt, minj);
    k_assign<<<(BS * A_N + 255) / 256, 256, 0, stream>>>(pd_scores, pd_bboxes, gt_bboxes,
                                                         gl_raw, cnt, minj,
                                                         posA, posO, fgList, fgCnt, out);
    k_norm<<<(FGCAP + 255) / 256, 256, 0, stream>>>(fgList, fgCnt, posA, posO, out);
}

// Round 2
// 234.078 us; speedup vs baseline: 1.0202x; 1.0202x over previous
//
#include <hip/hip_runtime.h>
#include <math.h>

// Problem constants
#define A_N   8400
#define BS    32
#define NGT   64
#define NC    80
#define TK    13
#define EPSF  1e-9f
#define CAP   1024          // dense per-(b,gt) candidate list capacity
#define JG    16            // gts per k_cand block (64 split in 4 groups)
#define NJG   4
#define NTILE 33            // ceil(8400/256)
#define PCAP  64            // LDS pool capacity per (block, gt)
#define NCAND (BS * NTILE * NJG)   // 4224 k_cand blocks
#define FGCAP (BS * NGT * TK)      // 26624: hard bound on fg anchors (<=13 picks/gt)

typedef float nt4 __attribute__((ext_vector_type(4)));   // native vec for nontemporal store

// Output layout (floats), concatenated in reference return order
#define OFF_LB 0
#define OFF_BB (BS * A_N)
#define OFF_SC (OFF_BB + BS * A_N * 4)
#define OFF_FG (OFF_SC + BS * A_N * NC)

// Workspace layout (byte offsets, all 256-aligned)
#define WS_CNT   0
#define WS_MINJ  (WS_CNT  + BS * A_N * 4)
#define WS_POSA  (WS_MINJ + BS * A_N * 4)
#define WS_POSO  (WS_POSA + BS * NGT * 4)
#define WS_CNT2  (WS_POSO + BS * NGT * 4)
#define WS_FGC   (WS_CNT2 + BS * NGT * 4)
#define WS_FGL   (WS_FGC  + 256)
#define WS_CAND  (WS_FGL  + FGCAP * 16)
// total ~= 19.4 MB

// NOTE (R7 lesson): software grid barriers (device-scope atomic spin) cost
// ~250 us EACH on MI355X. Separate kernel launches are 100x cheaper.
//
// NOTE (R9 post-mortem of R8): the compact fg-list append used a divergent
// per-lane atomicAdd(fgCnt,1) -> 21k serialized device-scope atomics on ONE
// cacheline; k_assign ballooned to 55.8 us (196 GB/s, VALUBusy 11% = pure
// serialization) and total regressed 210->239. Fix: wave-aggregated append
// (ballot + leader atomicAdd + mbcnt prefix), 64x fewer atomics; plus LDS
// staging of per-batch gt boxes/labels to kill the dependent global gather
// chain (cnt -> minj -> gl_raw -> gt_bboxes). k_assign regridded to 33
// blocks/batch so each block serves exactly one batch.

__device__ __forceinline__ float iou_f(float g0, float g1, float g2, float g3,
                                       float p0, float p1, float p2, float p3) {
    float ltx = fmaxf(g0, p0), lty = fmaxf(g1, p1);
    float rbx = fminf(g2, p2), rby = fminf(g3, p3);
    float ov  = fmaxf(rbx - ltx, 0.f) * fmaxf(rby - lty, 0.f);
    float a1  = fmaxf(g2 - g0, 0.f) * fmaxf(g3 - g1, 0.f);
    float a2  = fmaxf(p2 - p0, 0.f) * fmaxf(p3 - p1, 0.f);
    return ov / (a1 + a2 - ov + EPSF);
}

__device__ __forceinline__ int get_gl(const int* g, int flag64, int i) {
    return flag64 ? g[2 * i] : g[i];
}

// int64-vs-int32 gt_labels layout probe: wave 0 checks the high words of the
// first 64 entries. Valid in every lane of wave 0 only.
__device__ __forceinline__ int probe_flag64_wave0(const int* gl_raw, int tid) {
    int f64 = 0;
    if (tid < 64) {
        unsigned long long m = __ballot(gl_raw[2 * tid + 1] != 0);
        f64 = (m == 0ull);
    }
    return f64;
}

__device__ __forceinline__ unsigned long long shfl_xor_u64(unsigned long long x, int m) {
    int lo = __shfl_xor((int)(unsigned int)(x & 0xFFFFFFFFull), m, 64);
    int hi = __shfl_xor((int)(unsigned int)(x >> 32), m, 64);
    return ((unsigned long long)(unsigned int)hi << 32) | (unsigned int)lo;
}

// ---------------- Kernel 0: zero the small counter block ---------------------
// posA(2048) + posO(2048) + cnt2(2048) + fgCnt slot(64) = 6208 ints, contiguous.
__global__ __launch_bounds__(256) void k_zero(int* __restrict__ base) {
    int i = blockIdx.x * 256 + threadIdx.x;
    if (i < 3 * BS * NGT + 64) base[i] = 0;
}

// ---------------- Kernel 1: dense in-box sweep -> candidate lists ------------
__global__ __launch_bounds__(256) void k_cand(
    const float* __restrict__ pd_scores, const float* __restrict__ pd_bboxes,
    const float* __restrict__ anc, const int* __restrict__ gl_raw,
    const float* __restrict__ gt_bboxes, const float* __restrict__ mask_gt,
    int* __restrict__ cnt2, unsigned long long* __restrict__ cand,
    int* __restrict__ cnt, int* __restrict__ minj, float* __restrict__ out) {
    __shared__ float4 sgt[JG];
    __shared__ int    slbl[JG];
    __shared__ int    smask[JG];
    __shared__ int    cnt_lds[JG];
    __shared__ int    base_lds[JG];
    __shared__ unsigned long long pool[JG][PCAP];

    int bid  = blockIdx.x;
    int b    = bid / (NTILE * NJG);
    int rem  = bid % (NTILE * NJG);
    int tile = rem / NJG;
    int jg   = rem % NJG;
    int tid  = threadIdx.x;
    int a    = tile * 256 + tid;
    int jbase = b * NGT + jg * JG;

    int f64 = probe_flag64_wave0(gl_raw, tid);    // valid in wave 0 (tids 0..63)
    if (tid < JG) {                               // tid<16 is inside wave 0
        sgt[tid]   = ((const float4*)gt_bboxes)[jbase + tid];
        slbl[tid]  = get_gl(gl_raw, f64, jbase + tid);
        smask[tid] = (mask_gt[jbase + tid] != 0.f);
        cnt_lds[tid] = 0;
    }
    __syncthreads();

    bool act = (a < A_N);
    float2 an = make_float2(0.f, 0.f);
    float4 p  = make_float4(0.f, 0.f, 0.f, 0.f);
    const float* sc = pd_scores;
    if (act) {
        an = ((const float2*)anc)[a];
        p  = ((const float4*)pd_bboxes)[(size_t)b * A_N + a];
        sc = pd_scores + (size_t)b * A_N * NC + (size_t)a * NC;
    }

    // Phase A: hit detection + LDS append
    for (int j = 0; j < JG; j++) {
        if (!smask[j]) continue;                       // block-uniform
        if (!act) continue;
        float4 g = sgt[j];
        float d = fminf(fminf(an.x - g.x, an.y - g.y),
                        fminf(g.z - an.x, g.w - an.y));
        if (d > EPSF) {
            float iou = iou_f(g.x, g.y, g.z, g.w, p.x, p.y, p.z, p.w);
            float m = 0.f;
            if (iou > 0.f) {
                float s = sc[slbl[j]];
                m = s * powf(iou, 6.0f);               // identical op order (absmax 0.0)
            }
            unsigned long long key =
                ((unsigned long long)__float_as_uint(m) << 32) |
                (unsigned int)(~(unsigned int)a);      // (metric desc, anchor asc) under max
            int slot = atomicAdd(&cnt_lds[j], 1);      // LDS atomic
            if (slot < PCAP) {
                pool[j][slot] = key;
            } else {                                   // rare overflow: direct global
                int gs = atomicAdd(&cnt2[jbase + j], 1);
                if (gs < CAP) cand[(size_t)(jbase + j) * CAP + gs] = key;
            }
        }
    }
    __syncthreads();

    // Phase B: one global reservation per gt, issued in parallel
    if (tid < JG) {
        int c = min(cnt_lds[tid], PCAP);
        int bas = 0;
        if (c > 0) bas = atomicAdd(&cnt2[jbase + tid], c);
        base_lds[tid] = bas;
    }
    __syncthreads();

    // Phase C: flush LDS pools to global
    for (int j = 0; j < JG; j++) {
        int c = min(cnt_lds[j], PCAP);
        int bas = base_lds[j];
        for (int t = tid; t < c; t += 256) {
            int dst = bas + t;
            if (dst < CAP) cand[(size_t)(jbase + j) * CAP + dst] = pool[j][t];
        }
    }

    // Phase D (post-barrier): absorbed zero-fills; drain at kernel retire only
    {
        int gth = bid * 256 + tid;
        const int GS = NCAND * 256;
        nt4* scz = (nt4*)(out + OFF_SC);
        for (int t = gth; t < BS * A_N * (NC / 4); t += GS)
            __builtin_nontemporal_store((nt4)(0.f), &scz[t]);
        for (int t = gth; t < BS * A_N; t += GS) {
            cnt[t] = 0; minj[t] = 1 << 30;
        }
    }
}

// ---------------- Kernel 2: per-(b,gt) wave top-13 + scatter -----------------
template <int NT>
__device__ __forceinline__ void pick_body(
    int lane, int b, int j, int n, const unsigned long long* __restrict__ L,
    int* __restrict__ cnt, int* __restrict__ minj) {
    unsigned long long k0[NT];
    #pragma unroll
    for (int t = 0; t < NT; t++) {
        int i = t * 64 + lane;
        k0[t] = (i < n) ? L[i] : 0ULL;                 // 0 = empty (real keys nonzero)
    }

    unsigned int wanchor[TK];
    int P = 0;
    #pragma unroll
    for (int r = 0; r < TK; r++) {
        unsigned long long best = 0;
        #pragma unroll
        for (int t = 0; t < NT; t++) best = (k0[t] > best) ? k0[t] : best;
        for (int s = 1; s < 64; s <<= 1) {
            unsigned long long o = shfl_xor_u64(best, s);
            if (o > best) best = o;
        }
        if (!(best >> 32)) break;                      // out of positive metrics
        unsigned int aw = ~(unsigned int)(best & 0xFFFFFFFFull);
        wanchor[r] = aw;
        if (lane == 0) {
            atomicAdd(&cnt[b * A_N + (int)aw], 1);
            atomicMin(&minj[b * A_N + (int)aw], j);
        }
        #pragma unroll
        for (int t = 0; t < NT; t++) if (k0[t] == best) k0[t] = 0;
        P++;
    }

    // Fillers: top_k back-fills (13-P) lowest-index zero-metric anchors of the
    // full array; only in-box ones (all present as zero-metric candidates)
    // survive mask_in_gts. a is a filler iff a - |{positive winners < a}| < 13-P.
    if (P < TK) {
        int K = TK - P;
        #pragma unroll
        for (int t = 0; t < NT; t++) {
            unsigned long long key = k0[t];
            if (key != 0 && !(key >> 32)) {
                unsigned int a0 = ~(unsigned int)(key & 0xFFFFFFFFull);
                int off = 0;
                #pragma unroll
                for (int r = 0; r < TK; r++)
                    if (r < P && wanchor[r] < a0) off++;
                if ((int)a0 < K + off) {
                    atomicAdd(&cnt[b * A_N + (int)a0], 1);
                    atomicMin(&minj[b * A_N + (int)a0], j);
                }
            }
        }
    }
}

__global__ __launch_bounds__(256) void k_pick(
    const int* __restrict__ cnt2, const unsigned long long* __restrict__ cand,
    int* __restrict__ cnt, int* __restrict__ minj) {
    int lane = threadIdx.x & 63;
    int wave = threadIdx.x >> 6;
    int bj = blockIdx.x * 4 + wave;
    int b = bj >> 6, j = bj & 63;

    int n = min(cnt2[bj], CAP);
    if (n == 0) return;                                // wave-uniform
    const unsigned long long* L = cand + (size_t)bj * CAP;

    // wave-uniform tier dispatch: compile-time bounds keep k0[] in registers
    if (n <= 128)      pick_body<2>(lane, b, j, n, L, cnt, minj);
    else if (n <= 320) pick_body<5>(lane, b, j, n, L, cnt, minj);
    else               pick_body<16>(lane, b, j, n, L, cnt, minj);
}

// ---------------- Kernel 3: per-anchor assignment + labels/bboxes/fg ---------
// R9: grid = 33 blocks/batch (one batch per block); gt boxes + clamped labels
// staged in LDS (kills dependent global gathers); fg-list append is
// wave-aggregated (one atomicAdd per wave, not per lane).
__global__ __launch_bounds__(256) void k_assign(
    const float* __restrict__ pd_scores, const float* __restrict__ pd_bboxes,
    const float* __restrict__ gt_bboxes, const int* __restrict__ gl_raw,
    const int* __restrict__ cnt, const int* __restrict__ minj,
    unsigned int* posA, unsigned int* posO,
    int4* __restrict__ fgList, int* __restrict__ fgCnt, float* __restrict__ out) {
    __shared__ float4 sgb[NGT];
    __shared__ int    slb[NGT];

    int tid = threadIdx.x;
    int b   = blockIdx.x / NTILE;
    int a   = (blockIdx.x % NTILE) * 256 + tid;

    int f64 = probe_flag64_wave0(gl_raw, tid);    // valid in wave 0 (tids 0..63)
    if (tid < NGT) {                              // NGT==64 == wave 0 exactly
        sgb[tid] = ((const float4*)gt_bboxes)[b * NGT + tid];
        int l = get_gl(gl_raw, f64, b * NGT + tid);
        slb[tid] = (l < 0) ? 0 : l;               // labels pre-clamped
    }
    __syncthreads();

    bool act = (a < A_N);
    int i = b * A_N + a;

    // independent up-front loads
    int c = 0, mj = 0;
    float4 p = make_float4(0.f, 0.f, 0.f, 0.f);
    if (act) {
        c  = cnt[i];
        mj = minj[i];
        p  = ((const float4*)pd_bboxes)[i];
    }

    int jstar = 0;
    if (act) {
        if (c == 1) {
            jstar = mj;
        } else if (c > 1) {
            float bv = -1.f; int bj_ = 0;
            for (int j = 0; j < NGT; j++) {       // LDS-fed IoU sweep
                float4 g = sgb[j];
                float ov = iou_f(g.x, g.y, g.z, g.w, p.x, p.y, p.z, p.w);
                if (ov > bv) { bv = ov; bj_ = j; }
            }
            jstar = bj_;
        }
    }

    int fg = (act && c > 0) ? 1 : 0;
    float al = 0.f;
    int lbl = 0;
    if (act) {
        lbl = slb[jstar];
        out[OFF_LB + i] = (float)lbl;
        float4 g = sgb[jstar];
        ((float4*)(out + OFF_BB))[i] = g;
        out[OFF_FG + i] = (float)fg;
        if (fg) {
            float ov = iou_f(g.x, g.y, g.z, g.w, p.x, p.y, p.z, p.w);
            float s  = pd_scores[(size_t)i * NC + lbl];
            al = s * powf(ov, 6.0f);
            atomicMax((int*)&posA[b * NGT + jstar], __float_as_int(al));
            atomicMax((int*)&posO[b * NGT + jstar], __float_as_int(ov));
        }
    }

    // wave-aggregated compact-list append (R9: was per-lane atomicAdd on one
    // cacheline -> 21k serialized device atomics -> 55.8us kernel)
    unsigned long long mv = __ballot(fg != 0);
    if (mv) {
        int lane = tid & 63;
        int ldr  = (int)(__ffsll((unsigned long long)mv) - 1);
        int base = 0;
        if (lane == ldr) base = atomicAdd(fgCnt, __popcll(mv));
        base = __shfl(base, ldr, 64);
        if (fg) {
            int slot = base + (int)__popcll(mv & ((1ull << lane) - 1ull));
            fgList[slot] = make_int4(i | (lbl << 20), b * NGT + jstar,
                                     __float_as_int(al), 0);
        }
    }
}

// ---------------- Kernel 4: sparse norm scatter over compact fg list ---------
__global__ __launch_bounds__(256) void k_norm(
    const int4* __restrict__ fgList, const int* __restrict__ fgCnt,
    const unsigned int* __restrict__ posA, const unsigned int* __restrict__ posO,
    float* __restrict__ out) {
    int t = blockIdx.x * 256 + threadIdx.x;
    if (t >= *fgCnt) return;
    int4 r  = fgList[t];
    int i   = r.x & 0xFFFFF;
    int lbl = r.x >> 20;
    int bj  = r.y;
    float al = __int_as_float(r.z);
    float pa = __int_as_float((int)posA[bj]);
    float po = __int_as_float((int)posO[bj]);
    out[OFF_SC + (size_t)i * NC + lbl] = al * po / (pa + EPSF);
}

extern "C" void kernel_launch(void* const* d_in, const int* in_sizes, int n_in,
                              void* d_out, int out_size, void* d_ws, size_t ws_size,
                              hipStream_t stream) {
    const float* pd_scores = (const float*)d_in[0];
    const float* pd_bboxes = (const float*)d_in[1];
    const float* anc       = (const float*)d_in[2];
    const int*   gl_raw    = (const int*)d_in[3];
    const float* gt_bboxes = (const float*)d_in[4];
    const float* mask_gt   = (const float*)d_in[5];
    float* out = (float*)d_out;

    char* ws = (char*)d_ws;
    int*                cnt      = (int*)(ws + WS_CNT);
    int*                minj     = (int*)(ws + WS_MINJ);
    unsigned int*       posA     = (unsigned int*)(ws + WS_POSA);
    unsigned int*       posO     = (unsigned int*)(ws + WS_POSO);
    int*                cnt2     = (int*)(ws + WS_CNT2);
    int*                fgCnt    = (int*)(ws + WS_FGC);
    int4*               fgList   = (int4*)(ws + WS_FGL);
    unsigned long long* cand     = (unsigned long long*)(ws + WS_CAND);

    k_zero<<<25, 256, 0, stream>>>((int*)(ws + WS_POSA));
    k_cand<<<NCAND, 256, 0, stream>>>(pd_scores, pd_bboxes, anc, gl_raw,
                                      gt_bboxes, mask_gt, cnt2, cand,
                                      cnt, minj, out);
    k_pick<<<BS * NGT / 4, 256, 0, stream>>>(cnt2, cand, cnt, minj);
    k_assign<<<BS * NTILE, 256, 0, stream>>>(pd_scores, pd_bboxes, gt_bboxes,
                                             gl_raw, cnt, minj,
                                             posA, posO, fgList, fgCnt, out);
    k_norm<<<(FGCAP + 255) / 256, 256, 0, stream>>>(fgList, fgCnt, posA, posO, out);
}

// Round 3
// 210.619 us; speedup vs baseline: 1.1338x; 1.1114x over previous
//
#include <hip/hip_runtime.h>
#include <math.h>

// Problem constants
#define A_N   8400
#define BS    32
#define NGT   64
#define NC    80
#define TK    13
#define EPSF  1e-9f
#define CAP   1024          // dense per-(b,gt) candidate list capacity
#define JG    16            // gts per k_cand block (64 split in 4 groups)
#define NJG   4
#define NTILE 33            // ceil(8400/256)
#define PCAP  64            // LDS pool capacity per (block, gt)
#define NCAND (BS * NTILE * NJG)   // 4224 k_cand blocks
#define NASSIGN (BS * NTILE)       // 1056 k_assign blocks

typedef float nt4 __attribute__((ext_vector_type(4)));   // native vec for nontemporal store

// Output layout (floats), concatenated in reference return order
#define OFF_LB 0
#define OFF_BB (BS * A_N)
#define OFF_SC (OFF_BB + BS * A_N * 4)
#define OFF_FG (OFF_SC + BS * A_N * NC)

// Workspace layout (byte offsets, all 256-aligned)
#define WS_CNT   0
#define WS_MINJ  (WS_CNT  + BS * A_N * 4)
#define WS_POSA  (WS_MINJ + BS * A_N * 4)
#define WS_POSO  (WS_POSA + BS * NGT * 4)
#define WS_CNT2  (WS_POSO + BS * NGT * 4)
#define WS_FGBC  (WS_CNT2 + BS * NGT * 4)          // 1056 per-block fg counts
#define WS_FGL   (WS_FGBC + 4352)                  // segmented fg records
#define WS_CAND  (WS_FGL  + NASSIGN * 256 * 16)
// total ~= 23.3 MB

// NOTE (R7 lesson): software grid barriers (device-scope atomic spin) cost
// ~250 us EACH on MI355X. Separate kernel launches are 100x cheaper.
//
// NOTE (R9/R10): R8's per-lane atomicAdd(fgCnt) on ONE cacheline cost ~30us
// (21k serialized device-scope atomics). R9's wave-aggregation (4.2k leader
// atomics, same line) recovered only 4.7us total -> same-line fetch-adds
// still serialize at the coherence point at tens of ns each. R10 removes the
// global counter entirely: segmented compaction. Each k_assign block owns
// fgList[blockIdx*256..+255], ranks via ballot + LDS wave scan (NO global
// atomics), count to fgBlockCnt[blockIdx]; k_norm walks 1056 slices.
// Generalized lesson: no globally-ordered counters on this chip, ever.

__device__ __forceinline__ float iou_f(float g0, float g1, float g2, float g3,
                                       float p0, float p1, float p2, float p3) {
    float ltx = fmaxf(g0, p0), lty = fmaxf(g1, p1);
    float rbx = fminf(g2, p2), rby = fminf(g3, p3);
    float ov  = fmaxf(rbx - ltx, 0.f) * fmaxf(rby - lty, 0.f);
    float a1  = fmaxf(g2 - g0, 0.f) * fmaxf(g3 - g1, 0.f);
    float a2  = fmaxf(p2 - p0, 0.f) * fmaxf(p3 - p1, 0.f);
    return ov / (a1 + a2 - ov + EPSF);
}

__device__ __forceinline__ int get_gl(const int* g, int flag64, int i) {
    return flag64 ? g[2 * i] : g[i];
}

// int64-vs-int32 gt_labels layout probe: wave 0 checks the high words of the
// first 64 entries. Valid in every lane of wave 0 only.
__device__ __forceinline__ int probe_flag64_wave0(const int* gl_raw, int tid) {
    int f64 = 0;
    if (tid < 64) {
        unsigned long long m = __ballot(gl_raw[2 * tid + 1] != 0);
        f64 = (m == 0ull);
    }
    return f64;
}

__device__ __forceinline__ unsigned long long shfl_xor_u64(unsigned long long x, int m) {
    int lo = __shfl_xor((int)(unsigned int)(x & 0xFFFFFFFFull), m, 64);
    int hi = __shfl_xor((int)(unsigned int)(x >> 32), m, 64);
    return ((unsigned long long)(unsigned int)hi << 32) | (unsigned int)lo;
}

// ---------------- Kernel 0: zero the small counter block ---------------------
// posA(2048) + posO(2048) + cnt2(2048) = 6144 ints, contiguous. fgBlockCnt
// needs no zeroing (k_assign writes every entry unconditionally).
__global__ __launch_bounds__(256) void k_zero(int* __restrict__ base) {
    int i = blockIdx.x * 256 + threadIdx.x;
    if (i < 3 * BS * NGT) base[i] = 0;
}

// ---------------- Kernel 1: dense in-box sweep -> candidate lists ------------
__global__ __launch_bounds__(256) void k_cand(
    const float* __restrict__ pd_scores, const float* __restrict__ pd_bboxes,
    const float* __restrict__ anc, const int* __restrict__ gl_raw,
    const float* __restrict__ gt_bboxes, const float* __restrict__ mask_gt,
    int* __restrict__ cnt2, unsigned long long* __restrict__ cand,
    int* __restrict__ cnt, int* __restrict__ minj, float* __restrict__ out) {
    __shared__ float4 sgt[JG];
    __shared__ int    slbl[JG];
    __shared__ int    smask[JG];
    __shared__ int    cnt_lds[JG];
    __shared__ int    base_lds[JG];
    __shared__ unsigned long long pool[JG][PCAP];

    int bid  = blockIdx.x;
    int b    = bid / (NTILE * NJG);
    int rem  = bid % (NTILE * NJG);
    int tile = rem / NJG;
    int jg   = rem % NJG;
    int tid  = threadIdx.x;
    int a    = tile * 256 + tid;
    int jbase = b * NGT + jg * JG;

    int f64 = probe_flag64_wave0(gl_raw, tid);    // valid in wave 0 (tids 0..63)
    if (tid < JG) {                               // tid<16 is inside wave 0
        sgt[tid]   = ((const float4*)gt_bboxes)[jbase + tid];
        slbl[tid]  = get_gl(gl_raw, f64, jbase + tid);
        smask[tid] = (mask_gt[jbase + tid] != 0.f);
        cnt_lds[tid] = 0;
    }
    __syncthreads();

    bool act = (a < A_N);
    float2 an = make_float2(0.f, 0.f);
    float4 p  = make_float4(0.f, 0.f, 0.f, 0.f);
    const float* sc = pd_scores;
    if (act) {
        an = ((const float2*)anc)[a];
        p  = ((const float4*)pd_bboxes)[(size_t)b * A_N + a];
        sc = pd_scores + (size_t)b * A_N * NC + (size_t)a * NC;
    }

    // Phase A: hit detection + LDS append
    for (int j = 0; j < JG; j++) {
        if (!smask[j]) continue;                       // block-uniform
        if (!act) continue;
        float4 g = sgt[j];
        float d = fminf(fminf(an.x - g.x, an.y - g.y),
                        fminf(g.z - an.x, g.w - an.y));
        if (d > EPSF) {
            float iou = iou_f(g.x, g.y, g.z, g.w, p.x, p.y, p.z, p.w);
            float m = 0.f;
            if (iou > 0.f) {
                float s = sc[slbl[j]];
                m = s * powf(iou, 6.0f);               // identical op order (absmax 0.0)
            }
            unsigned long long key =
                ((unsigned long long)__float_as_uint(m) << 32) |
                (unsigned int)(~(unsigned int)a);      // (metric desc, anchor asc) under max
            int slot = atomicAdd(&cnt_lds[j], 1);      // LDS atomic
            if (slot < PCAP) {
                pool[j][slot] = key;
            } else {                                   // rare overflow: direct global
                int gs = atomicAdd(&cnt2[jbase + j], 1);
                if (gs < CAP) cand[(size_t)(jbase + j) * CAP + gs] = key;
            }
        }
    }
    __syncthreads();

    // Phase B: one global reservation per gt, issued in parallel
    if (tid < JG) {
        int c = min(cnt_lds[tid], PCAP);
        int bas = 0;
        if (c > 0) bas = atomicAdd(&cnt2[jbase + tid], c);
        base_lds[tid] = bas;
    }
    __syncthreads();

    // Phase C: flush LDS pools to global
    for (int j = 0; j < JG; j++) {
        int c = min(cnt_lds[j], PCAP);
        int bas = base_lds[j];
        for (int t = tid; t < c; t += 256) {
            int dst = bas + t;
            if (dst < CAP) cand[(size_t)(jbase + j) * CAP + dst] = pool[j][t];
        }
    }

    // Phase D (post-barrier): absorbed zero-fills; drain at kernel retire only
    {
        int gth = bid * 256 + tid;
        const int GS = NCAND * 256;
        nt4* scz = (nt4*)(out + OFF_SC);
        for (int t = gth; t < BS * A_N * (NC / 4); t += GS)
            __builtin_nontemporal_store((nt4)(0.f), &scz[t]);
        for (int t = gth; t < BS * A_N; t += GS) {
            cnt[t] = 0; minj[t] = 1 << 30;
        }
    }
}

// ---------------- Kernel 2: per-(b,gt) wave top-13 + scatter -----------------
template <int NT>
__device__ __forceinline__ void pick_body(
    int lane, int b, int j, int n, const unsigned long long* __restrict__ L,
    int* __restrict__ cnt, int* __restrict__ minj) {
    unsigned long long k0[NT];
    #pragma unroll
    for (int t = 0; t < NT; t++) {
        int i = t * 64 + lane;
        k0[t] = (i < n) ? L[i] : 0ULL;                 // 0 = empty (real keys nonzero)
    }

    unsigned int wanchor[TK];
    int P = 0;
    #pragma unroll
    for (int r = 0; r < TK; r++) {
        unsigned long long best = 0;
        #pragma unroll
        for (int t = 0; t < NT; t++) best = (k0[t] > best) ? k0[t] : best;
        for (int s = 1; s < 64; s <<= 1) {
            unsigned long long o = shfl_xor_u64(best, s);
            if (o > best) best = o;
        }
        if (!(best >> 32)) break;                      // out of positive metrics
        unsigned int aw = ~(unsigned int)(best & 0xFFFFFFFFull);
        wanchor[r] = aw;
        if (lane == 0) {
            atomicAdd(&cnt[b * A_N + (int)aw], 1);
            atomicMin(&minj[b * A_N + (int)aw], j);
        }
        #pragma unroll
        for (int t = 0; t < NT; t++) if (k0[t] == best) k0[t] = 0;
        P++;
    }

    // Fillers: top_k back-fills (13-P) lowest-index zero-metric anchors of the
    // full array; only in-box ones (all present as zero-metric candidates)
    // survive mask_in_gts. a is a filler iff a - |{positive winners < a}| < 13-P.
    if (P < TK) {
        int K = TK - P;
        #pragma unroll
        for (int t = 0; t < NT; t++) {
            unsigned long long key = k0[t];
            if (key != 0 && !(key >> 32)) {
                unsigned int a0 = ~(unsigned int)(key & 0xFFFFFFFFull);
                int off = 0;
                #pragma unroll
                for (int r = 0; r < TK; r++)
                    if (r < P && wanchor[r] < a0) off++;
                if ((int)a0 < K + off) {
                    atomicAdd(&cnt[b * A_N + (int)a0], 1);
                    atomicMin(&minj[b * A_N + (int)a0], j);
                }
            }
        }
    }
}

__global__ __launch_bounds__(256) void k_pick(
    const int* __restrict__ cnt2, const unsigned long long* __restrict__ cand,
    int* __restrict__ cnt, int* __restrict__ minj) {
    int lane = threadIdx.x & 63;
    int wave = threadIdx.x >> 6;
    int bj = blockIdx.x * 4 + wave;
    int b = bj >> 6, j = bj & 63;

    int n = min(cnt2[bj], CAP);
    if (n == 0) return;                                // wave-uniform
    const unsigned long long* L = cand + (size_t)bj * CAP;

    // wave-uniform tier dispatch: compile-time bounds keep k0[] in registers
    if (n <= 128)      pick_body<2>(lane, b, j, n, L, cnt, minj);
    else if (n <= 320) pick_body<5>(lane, b, j, n, L, cnt, minj);
    else               pick_body<16>(lane, b, j, n, L, cnt, minj);
}

// ---------------- Kernel 3: per-anchor assignment + labels/bboxes/fg ---------
// R10: segmented fg compaction — block-local ranks (ballot + LDS wave scan),
// block-owned fgList slice, per-block count. Zero global atomics on the hot
// path except the low-contention posA/posO maxes (2048 distinct lines).
__global__ __launch_bounds__(256) void k_assign(
    const float* __restrict__ pd_scores, const float* __restrict__ pd_bboxes,
    const float* __restrict__ gt_bboxes, const int* __restrict__ gl_raw,
    const int* __restrict__ cnt, const int* __restrict__ minj,
    unsigned int* posA, unsigned int* posO,
    int4* __restrict__ fgList, int* __restrict__ fgBlockCnt,
    float* __restrict__ out) {
    __shared__ float4 sgb[NGT];
    __shared__ int    slb[NGT];
    __shared__ int    swc[4];                     // per-wave fg counts

    int tid = threadIdx.x;
    int b   = blockIdx.x / NTILE;
    int a   = (blockIdx.x % NTILE) * 256 + tid;

    int f64 = probe_flag64_wave0(gl_raw, tid);    // valid in wave 0 (tids 0..63)
    if (tid < NGT) {                              // NGT==64 == wave 0 exactly
        sgb[tid] = ((const float4*)gt_bboxes)[b * NGT + tid];
        int l = get_gl(gl_raw, f64, b * NGT + tid);
        slb[tid] = (l < 0) ? 0 : l;               // labels pre-clamped
    }
    __syncthreads();

    bool act = (a < A_N);
    int i = b * A_N + a;

    // independent up-front loads
    int c = 0, mj = 0;
    float4 p = make_float4(0.f, 0.f, 0.f, 0.f);
    if (act) {
        c  = cnt[i];
        mj = minj[i];
        p  = ((const float4*)pd_bboxes)[i];
    }

    int jstar = 0;
    if (act) {
        if (c == 1) {
            jstar = mj;
        } else if (c > 1) {
            float bv = -1.f; int bj_ = 0;
            for (int j = 0; j < NGT; j++) {       // LDS-fed IoU sweep
                float4 g = sgb[j];
                float ov = iou_f(g.x, g.y, g.z, g.w, p.x, p.y, p.z, p.w);
                if (ov > bv) { bv = ov; bj_ = j; }
            }
            jstar = bj_;
        }
    }

    int fg = (act && c > 0) ? 1 : 0;
    float al = 0.f;
    int lbl = 0;
    if (act) {
        lbl = slb[jstar];
        out[OFF_LB + i] = (float)lbl;
        float4 g = sgb[jstar];
        ((float4*)(out + OFF_BB))[i] = g;
        out[OFF_FG + i] = (float)fg;
        if (fg) {
            float ov = iou_f(g.x, g.y, g.z, g.w, p.x, p.y, p.z, p.w);
            float s  = pd_scores[(size_t)i * NC + lbl];
            al = s * powf(ov, 6.0f);
            atomicMax((int*)&posA[b * NGT + jstar], __float_as_int(al));
            atomicMax((int*)&posO[b * NGT + jstar], __float_as_int(ov));
        }
    }

    // segmented compaction: block-local rank, block-owned slice, no global atomic
    int lane = tid & 63;
    int wv   = tid >> 6;
    unsigned long long mv = __ballot(fg != 0);
    if (lane == 0) swc[wv] = (int)__popcll(mv);
    __syncthreads();
    int w0 = swc[0], w1 = swc[1], w2 = swc[2], w3 = swc[3];
    if (fg) {
        int pre = (wv > 0 ? w0 : 0) + (wv > 1 ? w1 : 0) + (wv > 2 ? w2 : 0);
        int rank = pre + (int)__popcll(mv & ((1ull << lane) - 1ull));
        fgList[blockIdx.x * 256 + rank] =
            make_int4(i | (lbl << 20), b * NGT + jstar, __float_as_int(al), 0);
    }
    if (tid == 0) fgBlockCnt[blockIdx.x] = w0 + w1 + w2 + w3;
}

// ---------------- Kernel 4: sparse norm scatter over segmented fg list -------
__global__ __launch_bounds__(256) void k_norm(
    const int4* __restrict__ fgList, const int* __restrict__ fgBlockCnt,
    const unsigned int* __restrict__ posA, const unsigned int* __restrict__ posO,
    float* __restrict__ out) {
    int bb = blockIdx.x;
    int t  = threadIdx.x;
    int n  = fgBlockCnt[bb];                      // block-uniform
    if (t >= n) return;
    int4 r  = fgList[bb * 256 + t];
    int i   = r.x & 0xFFFFF;
    int lbl = r.x >> 20;
    int bj  = r.y;
    float al = __int_as_float(r.z);
    float pa = __int_as_float((int)posA[bj]);
    float po = __int_as_float((int)posO[bj]);
    out[OFF_SC + (size_t)i * NC + lbl] = al * po / (pa + EPSF);
}

extern "C" void kernel_launch(void* const* d_in, const int* in_sizes, int n_in,
                              void* d_out, int out_size, void* d_ws, size_t ws_size,
                              hipStream_t stream) {
    const float* pd_scores = (const float*)d_in[0];
    const float* pd_bboxes = (const float*)d_in[1];
    const float* anc       = (const float*)d_in[2];
    const int*   gl_raw    = (const int*)d_in[3];
    const float* gt_bboxes = (const float*)d_in[4];
    const float* mask_gt   = (const float*)d_in[5];
    float* out = (float*)d_out;

    char* ws = (char*)d_ws;
    int*                cnt      = (int*)(ws + WS_CNT);
    int*                minj     = (int*)(ws + WS_MINJ);
    unsigned int*       posA     = (unsigned int*)(ws + WS_POSA);
    unsigned int*       posO     = (unsigned int*)(ws + WS_POSO);
    int*                cnt2     = (int*)(ws + WS_CNT2);
    int*                fgBC     = (int*)(ws + WS_FGBC);
    int4*               fgList   = (int4*)(ws + WS_FGL);
    unsigned long long* cand     = (unsigned long long*)(ws + WS_CAND);

    k_zero<<<24, 256, 0, stream>>>((int*)(ws + WS_POSA));
    k_cand<<<NCAND, 256, 0, stream>>>(pd_scores, pd_bboxes, anc, gl_raw,
                                      gt_bboxes, mask_gt, cnt2, cand,
                                      cnt, minj, out);
    k_pick<<<BS * NGT / 4, 256, 0, stream>>>(cnt2, cand, cnt, minj);
    k_assign<<<NASSIGN, 256, 0, stream>>>(pd_scores, pd_bboxes, gt_bboxes,
                                          gl_raw, cnt, minj,
                                          posA, posO, fgList, fgBC, out);
    k_norm<<<NASSIGN, 256, 0, stream>>>(fgList, fgBC, posA, posO, out);
}

// Round 4
// 209.691 us; speedup vs baseline: 1.1389x; 1.0044x over previous
//
#include <hip/hip_runtime.h>
#include <math.h>

// Problem constants
#define A_N   8400
#define BS    32
#define NGT   64
#define NC    80
#define TK    13
#define EPSF  1e-9f
#define CAP   1024          // dense per-(b,gt) candidate list capacity
#define JG    16            // gts per k_cand block (64 split in 4 groups)
#define NJG   4
#define NTILE 33            // ceil(8400/256)
#define PCAP  64            // LDS pool capacity per (block, gt)
#define NCAND (BS * NTILE * NJG)   // 4224 k_cand blocks
#define NASSIGN (BS * NTILE)       // 1056 k_assign blocks
#define PKW   16            // pick-list slots per (b,gt) (max 13 used)

typedef float nt4 __attribute__((ext_vector_type(4)));   // native vec for nontemporal store

// Output layout (floats), concatenated in reference return order
#define OFF_LB 0
#define OFF_BB (BS * A_N)
#define OFF_SC (OFF_BB + BS * A_N * 4)
#define OFF_FG (OFF_SC + BS * A_N * NC)

// Workspace layout (byte offsets, all 256-aligned)
#define WS_POSA  0
#define WS_POSO  (WS_POSA + BS * NGT * 4)
#define WS_CNT2  (WS_POSO + BS * NGT * 4)
#define WS_PKC   (WS_CNT2 + BS * NGT * 4)              // 2048 pick counts
#define WS_PKL   (WS_PKC  + BS * NGT * 4)              // 2048*16 pick anchors
#define WS_FGBC  (WS_PKL  + BS * NGT * PKW * 4)        // 1056 per-block fg counts
#define WS_FGL   (WS_FGBC + 8192)                      // segmented fg records
#define WS_CAND  (WS_FGL  + NASSIGN * 256 * 16)
// total ~= 21.3 MB

// NOTE (R7 lesson): software grid barriers (device-scope atomic spin) cost
// ~250 us EACH on MI355X. Separate kernel launches are 100x cheaper.
//
// NOTE (R9/R10): globally-ordered counters serialize at the coherence point
// (~tens of ns per same-line fetch-add, cross-XCD). R8's per-lane atomicAdd
// on one line cost ~30us; R9's wave-aggregated version STILL cost ~25us;
// R10's segmented compaction (zero global atomics) recovered it all.
// Lesson: never funnel through one cacheline, aggregated or not.
//
// NOTE (R11): timed-region model: ~168us of harness poison fills (3x370MB
// fillBufferAligned @ ~6.5TB/s, fits R1/R2/R3 totals) + our kernels (~42us).
// This round removes the dense cnt/minj round-trip (17MB write + 8.6MB read
// + 26k scattered global atomics in k_pick) in favor of compact per-gt pick
// lists (107KB); k_assign rebuilds per-tile cnt/minj in LDS from its batch's
// <=832 picks. posA/posO zeroing folded into k_cand Phase D.

__device__ __forceinline__ float iou_f(float g0, float g1, float g2, float g3,
                                       float p0, float p1, float p2, float p3) {
    float ltx = fmaxf(g0, p0), lty = fmaxf(g1, p1);
    float rbx = fminf(g2, p2), rby = fminf(g3, p3);
    float ov  = fmaxf(rbx - ltx, 0.f) * fmaxf(rby - lty, 0.f);
    float a1  = fmaxf(g2 - g0, 0.f) * fmaxf(g3 - g1, 0.f);
    float a2  = fmaxf(p2 - p0, 0.f) * fmaxf(p3 - p1, 0.f);
    return ov / (a1 + a2 - ov + EPSF);
}

__device__ __forceinline__ int get_gl(const int* g, int flag64, int i) {
    return flag64 ? g[2 * i] : g[i];
}

// int64-vs-int32 gt_labels layout probe: wave 0 checks the high words of the
// first 64 entries. Valid in every lane of wave 0 only.
__device__ __forceinline__ int probe_flag64_wave0(const int* gl_raw, int tid) {
    int f64 = 0;
    if (tid < 64) {
        unsigned long long m = __ballot(gl_raw[2 * tid + 1] != 0);
        f64 = (m == 0ull);
    }
    return f64;
}

__device__ __forceinline__ unsigned long long shfl_xor_u64(unsigned long long x, int m) {
    int lo = __shfl_xor((int)(unsigned int)(x & 0xFFFFFFFFull), m, 64);
    int hi = __shfl_xor((int)(unsigned int)(x >> 32), m, 64);
    return ((unsigned long long)(unsigned int)hi << 32) | (unsigned int)lo;
}

// ---------------- Kernel 0: zero cnt2 only (2048 ints) -----------------------
__global__ __launch_bounds__(256) void k_zero(int* __restrict__ cnt2) {
    int i = blockIdx.x * 256 + threadIdx.x;
    if (i < BS * NGT) cnt2[i] = 0;
}

// ---------------- Kernel 1: dense in-box sweep -> candidate lists ------------
__global__ __launch_bounds__(256) void k_cand(
    const float* __restrict__ pd_scores, const float* __restrict__ pd_bboxes,
    const float* __restrict__ anc, const int* __restrict__ gl_raw,
    const float* __restrict__ gt_bboxes, const float* __restrict__ mask_gt,
    int* __restrict__ cnt2, unsigned long long* __restrict__ cand,
    int* __restrict__ posZero, float* __restrict__ out) {
    __shared__ float4 sgt[JG];
    __shared__ int    slbl[JG];
    __shared__ int    smask[JG];
    __shared__ int    cnt_lds[JG];
    __shared__ int    base_lds[JG];
    __shared__ unsigned long long pool[JG][PCAP];

    int bid  = blockIdx.x;
    int b    = bid / (NTILE * NJG);
    int rem  = bid % (NTILE * NJG);
    int tile = rem / NJG;
    int jg   = rem % NJG;
    int tid  = threadIdx.x;
    int a    = tile * 256 + tid;
    int jbase = b * NGT + jg * JG;

    int f64 = probe_flag64_wave0(gl_raw, tid);    // valid in wave 0 (tids 0..63)
    if (tid < JG) {                               // tid<16 is inside wave 0
        sgt[tid]   = ((const float4*)gt_bboxes)[jbase + tid];
        slbl[tid]  = get_gl(gl_raw, f64, jbase + tid);
        smask[tid] = (mask_gt[jbase + tid] != 0.f);
        cnt_lds[tid] = 0;
    }
    __syncthreads();

    bool act = (a < A_N);
    float2 an = make_float2(0.f, 0.f);
    float4 p  = make_float4(0.f, 0.f, 0.f, 0.f);
    const float* sc = pd_scores;
    if (act) {
        an = ((const float2*)anc)[a];
        p  = ((const float4*)pd_bboxes)[(size_t)b * A_N + a];
        sc = pd_scores + (size_t)b * A_N * NC + (size_t)a * NC;
    }

    // Phase A: hit detection + LDS append
    for (int j = 0; j < JG; j++) {
        if (!smask[j]) continue;                       // block-uniform
        if (!act) continue;
        float4 g = sgt[j];
        float d = fminf(fminf(an.x - g.x, an.y - g.y),
                        fminf(g.z - an.x, g.w - an.y));
        if (d > EPSF) {
            float iou = iou_f(g.x, g.y, g.z, g.w, p.x, p.y, p.z, p.w);
            float m = 0.f;
            if (iou > 0.f) {
                float s = sc[slbl[j]];
                m = s * powf(iou, 6.0f);               // identical op order (absmax 0.0)
            }
            unsigned long long key =
                ((unsigned long long)__float_as_uint(m) << 32) |
                (unsigned int)(~(unsigned int)a);      // (metric desc, anchor asc) under max
            int slot = atomicAdd(&cnt_lds[j], 1);      // LDS atomic
            if (slot < PCAP) {
                pool[j][slot] = key;
            } else {                                   // rare overflow: direct global
                int gs = atomicAdd(&cnt2[jbase + j], 1);
                if (gs < CAP) cand[(size_t)(jbase + j) * CAP + gs] = key;
            }
        }
    }
    __syncthreads();

    // Phase B: one global reservation per gt, issued in parallel
    if (tid < JG) {
        int c = min(cnt_lds[tid], PCAP);
        int bas = 0;
        if (c > 0) bas = atomicAdd(&cnt2[jbase + tid], c);
        base_lds[tid] = bas;
    }
    __syncthreads();

    // Phase C: flush LDS pools to global
    for (int j = 0; j < JG; j++) {
        int c = min(cnt_lds[j], PCAP);
        int bas = base_lds[j];
        for (int t = tid; t < c; t += 256) {
            int dst = bas + t;
            if (dst < CAP) cand[(size_t)(jbase + j) * CAP + dst] = pool[j][t];
        }
    }

    // Phase D (post-barrier): absorbed zero-fills; drain at kernel retire only.
    // R11: cnt/minj dense init removed (-17.2 MB); posA/posO zero folded here.
    {
        int gth = bid * 256 + tid;
        const int GS = NCAND * 256;
        nt4* scz = (nt4*)(out + OFF_SC);
        for (int t = gth; t < BS * A_N * (NC / 4); t += GS)
            __builtin_nontemporal_store((nt4)(0.f), &scz[t]);
        if (gth < 2 * BS * NGT) posZero[gth] = 0;      // posA+posO contiguous
    }
}

// ---------------- Kernel 2: per-(b,gt) wave top-13 -> compact pick list ------
// R11: emits <=13 anchor indices per gt (positives by lane 0, fillers via
// ballot-ranked compaction) instead of 26k scattered global atomics.
template <int NT>
__device__ __forceinline__ void pick_body(
    int lane, int bj, int n, const unsigned long long* __restrict__ L,
    int* __restrict__ pickList, int* __restrict__ pickCnt) {
    unsigned long long k0[NT];
    #pragma unroll
    for (int t = 0; t < NT; t++) {
        int i = t * 64 + lane;
        k0[t] = (i < n) ? L[i] : 0ULL;                 // 0 = empty (real keys nonzero)
    }

    unsigned int wanchor[TK];
    int P = 0;
    #pragma unroll
    for (int r = 0; r < TK; r++) {
        unsigned long long best = 0;
        #pragma unroll
        for (int t = 0; t < NT; t++) best = (k0[t] > best) ? k0[t] : best;
        for (int s = 1; s < 64; s <<= 1) {
            unsigned long long o = shfl_xor_u64(best, s);
            if (o > best) best = o;
        }
        if (!(best >> 32)) break;                      // out of positive metrics
        wanchor[r] = ~(unsigned int)(best & 0xFFFFFFFFull);
        #pragma unroll
        for (int t = 0; t < NT; t++) if (k0[t] == best) k0[t] = 0;
        P++;
    }

    // positives -> slots 0..P-1 (lane 0; static register indexing)
    #pragma unroll
    for (int r = 0; r < TK; r++)
        if (r < P && lane == 0) pickList[bj * PKW + r] = (int)wanchor[r];

    // Fillers: top_k back-fills (13-P) lowest-index zero-metric anchors of the
    // full array; only in-box ones (all present as zero-metric candidates)
    // survive mask_in_gts. a is a filler iff a - |{positive winners < a}| < 13-P.
    // Emitted via per-register ballot compaction (wave-uniform base).
    int base = P;
    if (P < TK) {
        int K = TK - P;
        #pragma unroll
        for (int t = 0; t < NT; t++) {
            unsigned long long key = k0[t];
            bool isf = (key != 0ULL) && !(key >> 32);
            unsigned int a0 = ~(unsigned int)(key & 0xFFFFFFFFull);
            int off = 0;
            #pragma unroll
            for (int r = 0; r < TK; r++)
                if (r < P && wanchor[r] < a0) off++;
            bool emit = isf && ((int)a0 < K + off);
            unsigned long long mv = __ballot(emit);
            if (emit) {
                int rank = (int)__popcll(mv & ((1ull << lane) - 1ull));
                pickList[bj * PKW + base + rank] = (int)a0;
            }
            base += (int)__popcll(mv);
        }
    }
    if (lane == 0) pickCnt[bj] = base;                 // total <= 13 by construction
}

__global__ __launch_bounds__(256) void k_pick(
    const int* __restrict__ cnt2, const unsigned long long* __restrict__ cand,
    int* __restrict__ pickList, int* __restrict__ pickCnt) {
    int lane = threadIdx.x & 63;
    int wave = threadIdx.x >> 6;
    int bj = blockIdx.x * 4 + wave;

    int n = min(cnt2[bj], CAP);
    if (n == 0) {                                      // wave-uniform
        if (lane == 0) pickCnt[bj] = 0;                // ws is poisoned: must write
        return;
    }
    const unsigned long long* L = cand + (size_t)bj * CAP;

    // wave-uniform tier dispatch: compile-time bounds keep k0[] in registers
    if (n <= 128)      pick_body<2>(lane, bj, n, L, pickList, pickCnt);
    else if (n <= 320) pick_body<5>(lane, bj, n, L, pickList, pickCnt);
    else               pick_body<16>(lane, bj, n, L, pickList, pickCnt);
}

// ---------------- Kernel 3: per-anchor assignment + labels/bboxes/fg ---------
// R11: per-tile cnt/minj rebuilt in LDS from the batch's <=832 picks (4 KB,
// L2-hot) — replaces the dense 8.6 MB cnt/minj read. Outputs nontemporal.
__global__ __launch_bounds__(256) void k_assign(
    const float* __restrict__ pd_scores, const float* __restrict__ pd_bboxes,
    const float* __restrict__ gt_bboxes, const int* __restrict__ gl_raw,
    const int* __restrict__ pickList, const int* __restrict__ pickCnt,
    unsigned int* posA, unsigned int* posO,
    int4* __restrict__ fgList, int* __restrict__ fgBlockCnt,
    float* __restrict__ out) {
    __shared__ float4 sgb[NGT];
    __shared__ int    slb[NGT];
    __shared__ int    scnt[256];
    __shared__ int    smnj[256];
    __shared__ int    swc[4];                     // per-wave fg counts

    int tid = threadIdx.x;
    int b   = blockIdx.x / NTILE;
    int lo  = (blockIdx.x % NTILE) * 256;
    int a   = lo + tid;

    scnt[tid] = 0;
    smnj[tid] = 1 << 30;
    int f64 = probe_flag64_wave0(gl_raw, tid);    // valid in wave 0 (tids 0..63)
    if (tid < NGT) {                              // NGT==64 == wave 0 exactly
        sgb[tid] = ((const float4*)gt_bboxes)[b * NGT + tid];
        int l = get_gl(gl_raw, f64, b * NGT + tid);
        slb[tid] = (l < 0) ? 0 : l;               // labels pre-clamped
    }
    __syncthreads();

    // scatter this batch's picks into the tile's cnt/minj (LDS)
    if (tid < NGT) {
        int j  = tid;
        int pc = pickCnt[b * NGT + j];
        for (int s = 0; s < pc; s++) {
            int rel = pickList[(b * NGT + j) * PKW + s] - lo;
            if ((unsigned)rel < 256u) {
                atomicAdd(&scnt[rel], 1);
                atomicMin(&smnj[rel], j);
            }
        }
    }
    __syncthreads();

    bool act = (a < A_N);
    int i = b * A_N + a;

    int c  = act ? scnt[tid] : 0;
    int mj = smnj[tid];
    float4 p = make_float4(0.f, 0.f, 0.f, 0.f);
    if (act) p = ((const float4*)pd_bboxes)[i];

    int jstar = 0;
    if (act) {
        if (c == 1) {
            jstar = mj;
        } else if (c > 1) {
            float bv = -1.f; int bj_ = 0;
            for (int j = 0; j < NGT; j++) {       // LDS-fed IoU sweep
                float4 g = sgb[j];
                float ov = iou_f(g.x, g.y, g.z, g.w, p.x, p.y, p.z, p.w);
                if (ov > bv) { bv = ov; bj_ = j; }
            }
            jstar = bj_;
        }
    }

    int fg = (act && c > 0) ? 1 : 0;
    float al = 0.f;
    int lbl = 0;
    if (act) {
        lbl = slb[jstar];
        __builtin_nontemporal_store((float)lbl, &out[OFF_LB + i]);
        float4 g = sgb[jstar];
        nt4 gv; gv.x = g.x; gv.y = g.y; gv.z = g.z; gv.w = g.w;
        __builtin_nontemporal_store(gv, &((nt4*)(out + OFF_BB))[i]);
        __builtin_nontemporal_store((float)fg, &out[OFF_FG + i]);
        if (fg) {
            float ov = iou_f(g.x, g.y, g.z, g.w, p.x, p.y, p.z, p.w);
            float s  = pd_scores[(size_t)i * NC + lbl];
            al = s * powf(ov, 6.0f);
            atomicMax((int*)&posA[b * NGT + jstar], __float_as_int(al));
            atomicMax((int*)&posO[b * NGT + jstar], __float_as_int(ov));
        }
    }

    // segmented compaction: block-local rank, block-owned slice, no global atomic
    int lane = tid & 63;
    int wv   = tid >> 6;
    unsigned long long mv = __ballot(fg != 0);
    if (lane == 0) swc[wv] = (int)__popcll(mv);
    __syncthreads();
    int w0 = swc[0], w1 = swc[1], w2 = swc[2], w3 = swc[3];
    if (fg) {
        int pre = (wv > 0 ? w0 : 0) + (wv > 1 ? w1 : 0) + (wv > 2 ? w2 : 0);
        int rank = pre + (int)__popcll(mv & ((1ull << lane) - 1ull));
        fgList[blockIdx.x * 256 + rank] =
            make_int4(i | (lbl << 20), b * NGT + jstar, __float_as_int(al), 0);
    }
    if (tid == 0) fgBlockCnt[blockIdx.x] = w0 + w1 + w2 + w3;
}

// ---------------- Kernel 4: sparse norm scatter over segmented fg list -------
__global__ __launch_bounds__(256) void k_norm(
    const int4* __restrict__ fgList, const int* __restrict__ fgBlockCnt,
    const unsigned int* __restrict__ posA, const unsigned int* __restrict__ posO,
    float* __restrict__ out) {
    int bb = blockIdx.x;
    int t  = threadIdx.x;
    int n  = fgBlockCnt[bb];                      // block-uniform
    if (t >= n) return;
    int4 r  = fgList[bb * 256 + t];
    int i   = r.x & 0xFFFFF;
    int lbl = r.x >> 20;
    int bj  = r.y;
    float al = __int_as_float(r.z);
    float pa = __int_as_float((int)posA[bj]);
    float po = __int_as_float((int)posO[bj]);
    out[OFF_SC + (size_t)i * NC + lbl] = al * po / (pa + EPSF);
}

extern "C" void kernel_launch(void* const* d_in, const int* in_sizes, int n_in,
                              void* d_out, int out_size, void* d_ws, size_t ws_size,
                              hipStream_t stream) {
    const float* pd_scores = (const float*)d_in[0];
    const float* pd_bboxes = (const float*)d_in[1];
    const float* anc       = (const float*)d_in[2];
    const int*   gl_raw    = (const int*)d_in[3];
    const float* gt_bboxes = (const float*)d_in[4];
    const float* mask_gt   = (const float*)d_in[5];
    float* out = (float*)d_out;

    char* ws = (char*)d_ws;
    unsigned int*       posA     = (unsigned int*)(ws + WS_POSA);
    unsigned int*       posO     = (unsigned int*)(ws + WS_POSO);
    int*                cnt2     = (int*)(ws + WS_CNT2);
    int*                pickCnt  = (int*)(ws + WS_PKC);
    int*                pickList = (int*)(ws + WS_PKL);
    int*                fgBC     = (int*)(ws + WS_FGBC);
    int4*               fgList   = (int4*)(ws + WS_FGL);
    unsigned long long* cand     = (unsigned long long*)(ws + WS_CAND);

    k_zero<<<8, 256, 0, stream>>>(cnt2);
    k_cand<<<NCAND, 256, 0, stream>>>(pd_scores, pd_bboxes, anc, gl_raw,
                                      gt_bboxes, mask_gt, cnt2, cand,
                                      (int*)(ws + WS_POSA), out);
    k_pick<<<BS * NGT / 4, 256, 0, stream>>>(cnt2, cand, pickList, pickCnt);
    k_assign<<<NASSIGN, 256, 0, stream>>>(pd_scores, pd_bboxes, gt_bboxes,
                                          gl_raw, pickList, pickCnt,
                                          posA, posO, fgList, fgBC, out);
    k_norm<<<NASSIGN, 256, 0, stream>>>(fgList, fgBC, posA, posO, out);
}